// Round 1
// baseline (1083.861 us; speedup 1.0000x reference)
//
#include <hip/hip_runtime.h>
#include <hip/hip_bf16.h>

// Problem constants (BertSelfAttention_979252544303)
#define SEQ   2048
#define BATCH 2
#define HID   1024
#define NHEAD 16
#define HDIM  64
#define BH    (BATCH * NHEAD)   // 32 flattened heads

// ---------------------------------------------------------------------------
// Kernel 1: projection GEMM  out[(b*NHEAD+h)][s][d] = x[s][b][:] @ W[:, h*64+d] + bias
// x: [SEQ*BATCH][HID] row-major (row r = s*BATCH + b), W: [HID][HID], bias: [HID]
// Tiling: BM=64, BN=64, BK=16; 256 threads; 4x4 micro-tile per thread.
// Column tile bn == head h (BN == HDIM == 64).
// ---------------------------------------------------------------------------
__global__ __launch_bounds__(256) void qkv_gemm(
    const float* __restrict__ x,
    const float* __restrict__ W,
    const float* __restrict__ bias,
    float* __restrict__ out)
{
    const int bn = blockIdx.x;      // 0..15 column tile == head index
    const int bm = blockIdx.y;      // 0..63 row tile
    const int t  = threadIdx.x;
    const int tn = t & 15;
    const int tm = t >> 4;

    __shared__ __align__(16) float As[16][68];  // [k][m], pad 68 -> 2-way max
    __shared__ __align__(16) float Bs[16][64];  // [k][n]

    float acc[4][4] = {};
    const int row0 = bm * 64;
    const int col0 = bn * 64;

    for (int kt = 0; kt < HID / 16; ++kt) {
        // A tile 64x16 (transposed store): thread loads one float4
        {
            const int r = t >> 2;
            const int c = (t & 3) * 4;
            const float4 a4 = *(const float4*)(x + (size_t)(row0 + r) * HID + kt * 16 + c);
            As[c + 0][r] = a4.x;
            As[c + 1][r] = a4.y;
            As[c + 2][r] = a4.z;
            As[c + 3][r] = a4.w;
            // B tile 16x64: thread loads one float4
            const int r2 = t >> 4;
            const int c2 = (t & 15) * 4;
            *(float4*)(&Bs[r2][c2]) =
                *(const float4*)(W + (size_t)(kt * 16 + r2) * HID + col0 + c2);
        }
        __syncthreads();

        #pragma unroll
        for (int k = 0; k < 16; ++k) {
            const float4 a = *(const float4*)(&As[k][tm * 4]);
            const float4 b = *(const float4*)(&Bs[k][tn * 4]);
            const float av[4] = {a.x, a.y, a.z, a.w};
            const float bv[4] = {b.x, b.y, b.z, b.w};
            #pragma unroll
            for (int i = 0; i < 4; ++i)
                #pragma unroll
                for (int j = 0; j < 4; ++j)
                    acc[i][j] += av[i] * bv[j];
        }
        __syncthreads();
    }

    // Epilogue: add bias, scatter to split-head layout [BH][SEQ][HDIM]
    const float4 b4 = *(const float4*)(bias + col0 + tn * 4);
    #pragma unroll
    for (int i = 0; i < 4; ++i) {
        const int m = row0 + tm * 4 + i;
        const int s  = m >> 1;      // BATCH == 2
        const int bb = m & 1;
        float4 o;
        o.x = acc[i][0] + b4.x;
        o.y = acc[i][1] + b4.y;
        o.z = acc[i][2] + b4.z;
        o.w = acc[i][3] + b4.w;
        *(float4*)(out + ((size_t)(bb * NHEAD + bn) * SEQ + s) * HDIM + tn * 4) = o;
    }
}

// ---------------------------------------------------------------------------
// Kernel 2: flash-style attention, fp32, online softmax.
// One block = (head n, 64-query-row tile). 256 threads, 4x4 micro-tile.
// q,k,v: [BH][SEQ][HDIM]; mask: [BATCH][1][SEQ][SEQ]; out: [SEQ][BATCH][HID]
// ---------------------------------------------------------------------------
__global__ __launch_bounds__(256) void attn(
    const float* __restrict__ q,
    const float* __restrict__ k,
    const float* __restrict__ v,
    const float* __restrict__ mask,
    float* __restrict__ out)
{
    const int qb = blockIdx.x;   // 0..31 query tile
    const int n  = blockIdx.y;   // 0..31 flattened head
    const int t  = threadIdx.x;
    const int tn = t & 15;
    const int tm = t >> 4;
    const int bb = n >> 4;       // batch  (n = b*NHEAD + h)
    const int hh = n & 15;       // head

    __shared__ __align__(16) float Qs[64][68];
    __shared__ __align__(16) float Ks[64][68];
    __shared__ __align__(16) float Vs[64][68];
    __shared__ __align__(16) float Ps[64][68];

    // Load Q tile (contiguous 64x64 block in global)
    const float* qbase = q + ((size_t)n * SEQ + qb * 64) * HDIM;
    #pragma unroll
    for (int u = 0; u < 4; ++u) {
        const int f = u * 256 + t;        // float4 index 0..1023
        const int r = f >> 4;
        const int c = (f & 15) * 4;
        *(float4*)(&Qs[r][c]) = *(const float4*)(qbase + r * HDIM + c);
    }

    float accv[4][4] = {};
    float mstate[4], lstate[4];
    #pragma unroll
    for (int i = 0; i < 4; ++i) { mstate[i] = -1e30f; lstate[i] = 0.0f; }

    const float* kbase = k + (size_t)n * SEQ * HDIM;
    const float* vbase = v + (size_t)n * SEQ * HDIM;
    const float scale = 0.125f;   // 1/sqrt(64)

    for (int kt = 0; kt < SEQ / 64; ++kt) {
        // Load K and V tiles
        #pragma unroll
        for (int u = 0; u < 4; ++u) {
            const int f = u * 256 + t;
            const int r = f >> 4;
            const int c = (f & 15) * 4;
            *(float4*)(&Ks[r][c]) = *(const float4*)(kbase + (size_t)(kt * 64 + r) * HDIM + c);
            *(float4*)(&Vs[r][c]) = *(const float4*)(vbase + (size_t)(kt * 64 + r) * HDIM + c);
        }
        __syncthreads();

        // Scores: sc[i][j] = Q[tm*4+i] . K[tn*4+j]
        float sc[4][4] = {};
        #pragma unroll
        for (int d4 = 0; d4 < 16; ++d4) {
            float4 qa[4], kb[4];
            #pragma unroll
            for (int i = 0; i < 4; ++i) qa[i] = *(const float4*)(&Qs[tm * 4 + i][d4 * 4]);
            #pragma unroll
            for (int j = 0; j < 4; ++j) kb[j] = *(const float4*)(&Ks[tn * 4 + j][d4 * 4]);
            #pragma unroll
            for (int i = 0; i < 4; ++i)
                #pragma unroll
                for (int j = 0; j < 4; ++j)
                    sc[i][j] += qa[i].x * kb[j].x + qa[i].y * kb[j].y +
                                qa[i].z * kb[j].z + qa[i].w * kb[j].w;
        }

        // scale + additive mask
        const float* mrow = mask + ((size_t)bb * SEQ + qb * 64 + tm * 4) * SEQ + kt * 64 + tn * 4;
        #pragma unroll
        for (int i = 0; i < 4; ++i) {
            const float4 m4 = *(const float4*)(mrow + (size_t)i * SEQ);
            sc[i][0] = sc[i][0] * scale + m4.x;
            sc[i][1] = sc[i][1] * scale + m4.y;
            sc[i][2] = sc[i][2] * scale + m4.z;
            sc[i][3] = sc[i][3] * scale + m4.w;
        }

        // Online softmax update per row
        #pragma unroll
        for (int i = 0; i < 4; ++i) {
            float rmax = fmaxf(fmaxf(sc[i][0], sc[i][1]), fmaxf(sc[i][2], sc[i][3]));
            #pragma unroll
            for (int off = 1; off < 16; off <<= 1)
                rmax = fmaxf(rmax, __shfl_xor(rmax, off));
            const float mnew  = fmaxf(mstate[i], rmax);
            const float alpha = __expf(mstate[i] - mnew);
            float rsum = 0.0f;
            #pragma unroll
            for (int j = 0; j < 4; ++j) {
                sc[i][j] = __expf(sc[i][j] - mnew);
                rsum += sc[i][j];
            }
            #pragma unroll
            for (int off = 1; off < 16; off <<= 1)
                rsum += __shfl_xor(rsum, off);
            lstate[i] = lstate[i] * alpha + rsum;
            mstate[i] = mnew;
            #pragma unroll
            for (int j = 0; j < 4; ++j) accv[i][j] *= alpha;
            // stash P tile
            float4 p4;
            p4.x = sc[i][0]; p4.y = sc[i][1]; p4.z = sc[i][2]; p4.w = sc[i][3];
            *(float4*)(&Ps[tm * 4 + i][tn * 4]) = p4;
        }
        __syncthreads();

        // PV: accv[i][j] += sum_kk P[qi][kk] * V[kk][d]
        for (int kk = 0; kk < 64; ++kk) {
            const float4 v4 = *(const float4*)(&Vs[kk][tn * 4]);
            #pragma unroll
            for (int i = 0; i < 4; ++i) {
                const float p = Ps[tm * 4 + i][kk];
                accv[i][0] += p * v4.x;
                accv[i][1] += p * v4.y;
                accv[i][2] += p * v4.z;
                accv[i][3] += p * v4.w;
            }
        }
        __syncthreads();
    }

    // Epilogue: normalize and write out[s][b][h*64+d]
    #pragma unroll
    for (int i = 0; i < 4; ++i) {
        const float inv = 1.0f / lstate[i];
        float4 o;
        o.x = accv[i][0] * inv;
        o.y = accv[i][1] * inv;
        o.z = accv[i][2] * inv;
        o.w = accv[i][3] * inv;
        const int s = qb * 64 + tm * 4 + i;
        *(float4*)(out + ((size_t)s * BATCH + bb) * HID + hh * 64 + tn * 4) = o;
    }
}

// ---------------------------------------------------------------------------
extern "C" void kernel_launch(void* const* d_in, const int* in_sizes, int n_in,
                              void* d_out, int out_size, void* d_ws, size_t ws_size,
                              hipStream_t stream) {
    const float* x    = (const float*)d_in[0];
    const float* mask = (const float*)d_in[1];
    const float* Wq   = (const float*)d_in[2];
    const float* bq   = (const float*)d_in[3];
    const float* Wk   = (const float*)d_in[4];
    const float* bk   = (const float*)d_in[5];
    const float* Wv   = (const float*)d_in[6];
    const float* bv   = (const float*)d_in[7];
    float* out = (float*)d_out;

    const size_t per = (size_t)BH * SEQ * HDIM;   // 4.19M floats = 16 MB
    float* qw = (float*)d_ws;
    float* kw = qw + per;
    float* vw = kw + per;

    dim3 gblk(256);
    dim3 ggrid(HID / 64, (SEQ * BATCH) / 64);     // (16, 64)
    qkv_gemm<<<ggrid, gblk, 0, stream>>>(x, Wq, bq, qw);
    qkv_gemm<<<ggrid, gblk, 0, stream>>>(x, Wk, bk, kw);
    qkv_gemm<<<ggrid, gblk, 0, stream>>>(x, Wv, bv, vw);

    dim3 agrid(SEQ / 64, BH);                     // (32, 32)
    attn<<<agrid, gblk, 0, stream>>>(qw, kw, vw, mask, out);
}

// Round 2
// 605.865 us; speedup vs baseline: 1.7889x; 1.7889x over previous
//
#include <hip/hip_runtime.h>
#include <hip/hip_bf16.h>

// Problem constants (BertSelfAttention_979252544303)
#define SEQ   2048
#define BATCH 2
#define HID   1024
#define NHEAD 16
#define HDIM  64
#define BH    (BATCH * NHEAD)   // 32 flattened heads

using short8  = __attribute__((ext_vector_type(8))) short;
using floatx4 = __attribute__((ext_vector_type(4))) float;

// float -> bf16 (RNE), bit-exact with __float2bfloat16 for normals
static __device__ __forceinline__ unsigned short f2bf(float f) {
    unsigned int u = __builtin_bit_cast(unsigned int, f);
    u += 0x7fffu + ((u >> 16) & 1u);
    return (unsigned short)(u >> 16);
}

// ---------------------------------------------------------------------------
// Kernel 1: projection GEMM (fp32 compute, bf16 output).
// MODE 0: out[(b*NHEAD+h)][s][d] bf16        (Q, K)
// MODE 1: out[(b*NHEAD+h)][d][s] bf16        (V, transposed for PV B-frags)
// x: [SEQ*BATCH][HID] (row r = s*BATCH+b), W: [HID][HID], bias: [HID]
// BM=64, BN=64, BK=16; 256 threads; 4x4 micro-tile. bn == head index.
// ---------------------------------------------------------------------------
template<int MODE>
__global__ __launch_bounds__(256) void qkv_gemm(
    const float* __restrict__ x,
    const float* __restrict__ W,
    const float* __restrict__ bias,
    unsigned short* __restrict__ out)
{
    const int bn = blockIdx.x;      // 0..15 column tile == head
    const int bm = blockIdx.y;      // 0..63 row tile
    const int t  = threadIdx.x;
    const int tn = t & 15;
    const int tm = t >> 4;

    __shared__ __align__(16) float As[16][68];  // [k][m]
    __shared__ __align__(16) float Bs[16][64];  // [k][n]

    float acc[4][4] = {};
    const int row0 = bm * 64;
    const int col0 = bn * 64;

    for (int kt = 0; kt < HID / 16; ++kt) {
        {
            const int r = t >> 2;
            const int c = (t & 3) * 4;
            const float4 a4 = *(const float4*)(x + (size_t)(row0 + r) * HID + kt * 16 + c);
            As[c + 0][r] = a4.x;
            As[c + 1][r] = a4.y;
            As[c + 2][r] = a4.z;
            As[c + 3][r] = a4.w;
            const int r2 = t >> 4;
            const int c2 = (t & 15) * 4;
            *(float4*)(&Bs[r2][c2]) =
                *(const float4*)(W + (size_t)(kt * 16 + r2) * HID + col0 + c2);
        }
        __syncthreads();

        #pragma unroll
        for (int k = 0; k < 16; ++k) {
            const float4 a = *(const float4*)(&As[k][tm * 4]);
            const float4 b = *(const float4*)(&Bs[k][tn * 4]);
            const float av[4] = {a.x, a.y, a.z, a.w};
            const float bv[4] = {b.x, b.y, b.z, b.w};
            #pragma unroll
            for (int i = 0; i < 4; ++i)
                #pragma unroll
                for (int j = 0; j < 4; ++j)
                    acc[i][j] += av[i] * bv[j];
        }
        __syncthreads();
    }

    const float4 b4 = *(const float4*)(bias + col0 + tn * 4);
    const float bv[4] = {b4.x, b4.y, b4.z, b4.w};

    if (MODE == 0) {
        #pragma unroll
        for (int i = 0; i < 4; ++i) {
            const int m = row0 + tm * 4 + i;
            const int s  = m >> 1;      // BATCH == 2
            const int bb = m & 1;
            ushort4 o;
            o.x = f2bf(acc[i][0] + bv[0]);
            o.y = f2bf(acc[i][1] + bv[1]);
            o.z = f2bf(acc[i][2] + bv[2]);
            o.w = f2bf(acc[i][3] + bv[3]);
            *(ushort4*)(out + ((size_t)(bb * NHEAD + bn) * SEQ + s) * HDIM + tn * 4) = o;
        }
    } else {
        // rows m, m+1, m+2, m+3 with m even: (s0,b0),(s0,b1),(s0+1,b0),(s0+1,b1)
        const int s0 = (row0 + tm * 4) >> 1;
        #pragma unroll
        for (int j = 0; j < 4; ++j) {
            const int d = tn * 4 + j;   // within-head dim
            ushort2 w0, w1;
            w0.x = f2bf(acc[0][j] + bv[j]);
            w0.y = f2bf(acc[2][j] + bv[j]);
            w1.x = f2bf(acc[1][j] + bv[j]);
            w1.y = f2bf(acc[3][j] + bv[j]);
            *(ushort2*)(out + ((size_t)(0 * NHEAD + bn) * HDIM + d) * SEQ + s0) = w0;
            *(ushort2*)(out + ((size_t)(1 * NHEAD + bn) * HDIM + d) * SEQ + s0) = w1;
        }
    }
}

// ---------------------------------------------------------------------------
// Kernel 2: flash attention, bf16 MFMA (16x16x32), fp32 online softmax.
// One block = (head n, 64-query tile), 4 waves, wave owns 16 q-rows.
// Computes S^T = K @ Q^T so softmax rows live in C-frag columns (lane&15).
// q,k: [BH][SEQ][64] bf16; vt: [BH][64][SEQ] bf16; mask: [B][1][S][S] fp32;
// out: [SEQ][BATCH][HID] fp32.
// ---------------------------------------------------------------------------
__global__ __launch_bounds__(256) void attn_mfma(
    const unsigned short* __restrict__ q,
    const unsigned short* __restrict__ k,
    const unsigned short* __restrict__ vt,
    const float* __restrict__ mask,
    float* __restrict__ out)
{
    const int qb   = blockIdx.x;   // 0..31 query tile
    const int n    = blockIdx.y;   // 0..31 flattened head
    const int t    = threadIdx.x;
    const int wave = t >> 6;
    const int lane = t & 63;
    const int l15  = lane & 15;
    const int quad = lane >> 4;
    const int bb   = n >> 4;       // batch
    const int hh   = n & 15;       // head

    // rows padded to 72 bf16 (144 B = 36 banks -> 2-way aliasing, free)
    __shared__ __align__(16) unsigned short Qs[64][72];
    __shared__ __align__(16) unsigned short Ks[64][72];
    __shared__ __align__(16) unsigned short Vs[64][72];  // [d][key]
    __shared__ __align__(16) unsigned short Ps[64][72];  // [qrow][key], wave-private rows

    // stage Q tile (64 rows x 64 bf16 = 512 chunks of 8 bf16)
    const unsigned short* qbase = q + ((size_t)n * SEQ + qb * 64) * HDIM;
    {
        int c = t, r = c >> 3, c8 = (c & 7) * 8;
        *(uint4*)&Qs[r][c8] = *(const uint4*)(qbase + r * HDIM + c8);
        c = t + 256; r = c >> 3; c8 = (c & 7) * 8;
        *(uint4*)&Qs[r][c8] = *(const uint4*)(qbase + r * HDIM + c8);
    }

    floatx4 Of[4];
    #pragma unroll
    for (int nt = 0; nt < 4; ++nt) Of[nt] = (floatx4){0.f, 0.f, 0.f, 0.f};
    float mst = -1e30f, lst = 0.0f;
    const float scale = 0.125f;    // 1/sqrt(64)

    const int qrow_g = qb * 64 + wave * 16 + l15;          // this lane's softmax row
    const float* mrow = mask + ((size_t)bb * SEQ + qrow_g) * SEQ;
    const unsigned short* kbase = k + (size_t)n * SEQ * HDIM;
    const unsigned short* vbase = vt + (size_t)n * HDIM * SEQ;

    for (int kt = 0; kt < SEQ / 64; ++kt) {
        __syncthreads();   // previous tile fully consumed
        {
            const unsigned short* kb = kbase + (size_t)(kt * 64) * HDIM;
            const unsigned short* vb = vbase + kt * 64;
            int c = t, r = c >> 3, c8 = (c & 7) * 8;
            *(uint4*)&Ks[r][c8] = *(const uint4*)(kb + r * HDIM + c8);
            *(uint4*)&Vs[r][c8] = *(const uint4*)(vb + (size_t)r * SEQ + c8);
            c = t + 256; r = c >> 3; c8 = (c & 7) * 8;
            *(uint4*)&Ks[r][c8] = *(const uint4*)(kb + r * HDIM + c8);
            *(uint4*)&Vs[r][c8] = *(const uint4*)(vb + (size_t)r * SEQ + c8);
        }
        __syncthreads();

        // S^T = K(64x64) @ Q^T(64x16 per wave): A=K rows, B=Q rows
        floatx4 Sf[4];
        #pragma unroll
        for (int mt = 0; mt < 4; ++mt) {
            floatx4 c = (floatx4){0.f, 0.f, 0.f, 0.f};
            #pragma unroll
            for (int ks = 0; ks < 2; ++ks) {
                short8 a = *(const short8*)&Ks[mt * 16 + l15][ks * 32 + quad * 8];
                short8 b = *(const short8*)&Qs[wave * 16 + l15][ks * 32 + quad * 8];
                c = __builtin_amdgcn_mfma_f32_16x16x32_bf16(a, b, c, 0, 0, 0);
            }
            Sf[mt] = c;
        }

        // scale + mask; lane holds S[key = mt*16+quad*4+r][qrow = l15]
        float sc[4][4];
        float rmax = -1e30f;
        #pragma unroll
        for (int mt = 0; mt < 4; ++mt) {
            const float4 m4 = *(const float4*)(mrow + kt * 64 + mt * 16 + quad * 4);
            const float mv[4] = {m4.x, m4.y, m4.z, m4.w};
            #pragma unroll
            for (int r = 0; r < 4; ++r) {
                sc[mt][r] = Sf[mt][r] * scale + mv[r];
                rmax = fmaxf(rmax, sc[mt][r]);
            }
        }
        rmax = fmaxf(rmax, __shfl_xor(rmax, 16));
        rmax = fmaxf(rmax, __shfl_xor(rmax, 32));

        const float mnew  = fmaxf(mst, rmax);
        const float alpha = __expf(mst - mnew);
        float rsum = 0.0f;
        #pragma unroll
        for (int mt = 0; mt < 4; ++mt)
            #pragma unroll
            for (int r = 0; r < 4; ++r) {
                const float p = __expf(sc[mt][r] - mnew);
                sc[mt][r] = p;
                rsum += p;
            }
        rsum += __shfl_xor(rsum, 16);
        rsum += __shfl_xor(rsum, 32);
        lst = lst * alpha + rsum;
        mst = mnew;

        // O-frag rows are quad*4+r (C-layout) but alpha indexes row l15 -> shfl
        {
            const float a0 = __shfl(alpha, quad * 4 + 0);
            const float a1 = __shfl(alpha, quad * 4 + 1);
            const float a2 = __shfl(alpha, quad * 4 + 2);
            const float a3 = __shfl(alpha, quad * 4 + 3);
            #pragma unroll
            for (int nt = 0; nt < 4; ++nt) {
                Of[nt][0] *= a0; Of[nt][1] *= a1;
                Of[nt][2] *= a2; Of[nt][3] *= a3;
            }
        }

        // stash P^T -> Ps[qrow][key] bf16 (wave-private rows, no barrier)
        #pragma unroll
        for (int mt = 0; mt < 4; ++mt) {
            ushort4 pk;
            pk.x = f2bf(sc[mt][0]);
            pk.y = f2bf(sc[mt][1]);
            pk.z = f2bf(sc[mt][2]);
            pk.w = f2bf(sc[mt][3]);
            *(ushort4*)&Ps[wave * 16 + l15][mt * 16 + quad * 4] = pk;
        }

        // PV: O(16 x 64) += P(16x64) @ V(64x64); A=P rows, B=V^T rows
        #pragma unroll
        for (int ks = 0; ks < 2; ++ks) {
            short8 a = *(const short8*)&Ps[wave * 16 + l15][ks * 32 + quad * 8];
            #pragma unroll
            for (int nt = 0; nt < 4; ++nt) {
                short8 b = *(const short8*)&Vs[nt * 16 + l15][ks * 32 + quad * 8];
                Of[nt] = __builtin_amdgcn_mfma_f32_16x16x32_bf16(a, b, Of[nt], 0, 0, 0);
            }
        }
    }

    // Epilogue: O rows = quad*4+r, cols = nt*16+l15; l lives at lane (quad*4+r)
    #pragma unroll
    for (int r = 0; r < 4; ++r) {
        const float lrow = __shfl(lst, quad * 4 + r);
        const float inv  = 1.0f / lrow;
        const int s = qb * 64 + wave * 16 + quad * 4 + r;
        float* orow = out + ((size_t)s * BATCH + bb) * HID + hh * 64;
        #pragma unroll
        for (int nt = 0; nt < 4; ++nt)
            orow[nt * 16 + l15] = Of[nt][r] * inv;
    }
}

// ---------------------------------------------------------------------------
extern "C" void kernel_launch(void* const* d_in, const int* in_sizes, int n_in,
                              void* d_out, int out_size, void* d_ws, size_t ws_size,
                              hipStream_t stream) {
    const float* x    = (const float*)d_in[0];
    const float* mask = (const float*)d_in[1];
    const float* Wq   = (const float*)d_in[2];
    const float* bq   = (const float*)d_in[3];
    const float* Wk   = (const float*)d_in[4];
    const float* bk   = (const float*)d_in[5];
    const float* Wv   = (const float*)d_in[6];
    const float* bv   = (const float*)d_in[7];
    float* out = (float*)d_out;

    const size_t per = (size_t)BH * SEQ * HDIM;   // 4.19M bf16 = 8 MB each
    unsigned short* qw = (unsigned short*)d_ws;
    unsigned short* kw = qw + per;
    unsigned short* vw = kw + per;

    dim3 gblk(256);
    dim3 ggrid(HID / 64, (SEQ * BATCH) / 64);     // (16, 64)
    qkv_gemm<0><<<ggrid, gblk, 0, stream>>>(x, Wq, bq, qw);
    qkv_gemm<0><<<ggrid, gblk, 0, stream>>>(x, Wk, bk, kw);
    qkv_gemm<1><<<ggrid, gblk, 0, stream>>>(x, Wv, bv, vw);

    dim3 agrid(SEQ / 64, BH);                     // (32, 32)
    attn_mfma<<<agrid, gblk, 0, stream>>>(qw, kw, vw, mask, out);
}

// Round 3
// 271.406 us; speedup vs baseline: 3.9935x; 2.2323x over previous
//
#include <hip/hip_runtime.h>
#include <hip/hip_bf16.h>

// Problem constants (BertSelfAttention_979252544303)
#define SEQ   2048
#define BATCH 2
#define HID   1024
#define NHEAD 16
#define HDIM  64
#define BH    (BATCH * NHEAD)   // 32 flattened heads

using short8  = __attribute__((ext_vector_type(8))) short;
using floatx4 = __attribute__((ext_vector_type(4))) float;

// float -> bf16 (RNE)
static __device__ __forceinline__ unsigned short f2bf(float f) {
    unsigned int u = __builtin_bit_cast(unsigned int, f);
    u += 0x7fffu + ((u >> 16) & 1u);
    return (unsigned short)(u >> 16);
}

#define GLD16(gp, lp)                                                        \
    __builtin_amdgcn_global_load_lds(                                        \
        (const __attribute__((address_space(1))) void*)(gp),                 \
        (__attribute__((address_space(3))) void*)(lp), 16, 0, 0)

// ---------------------------------------------------------------------------
// Prep 1: x fp32 [4096][1024] -> bf16 (straight). 1 float4 per thread.
// ---------------------------------------------------------------------------
__global__ __launch_bounds__(256) void convert_x(
    const float* __restrict__ x, unsigned short* __restrict__ xb)
{
    const int i = blockIdx.x * 256 + threadIdx.x;   // 0 .. 1048575
    const float4 v = ((const float4*)x)[i];
    ushort4 o;
    o.x = f2bf(v.x); o.y = f2bf(v.y); o.z = f2bf(v.z); o.w = f2bf(v.w);
    ((ushort4*)xb)[i] = o;
}

// ---------------------------------------------------------------------------
// Prep 2: W fp32 [k][n] -> wt bf16 [n][k], tiled transpose. z selects Q/K/V.
// ---------------------------------------------------------------------------
__global__ __launch_bounds__(256) void transpose_w(
    const float* __restrict__ Wq, const float* __restrict__ Wk,
    const float* __restrict__ Wv, unsigned short* __restrict__ wt)
{
    const float* W = (blockIdx.z == 0) ? Wq : (blockIdx.z == 1) ? Wk : Wv;
    unsigned short* out = wt + (size_t)blockIdx.z * HID * HID;
    __shared__ float tile[32][33];
    const int tx = threadIdx.x & 31, ty = threadIdx.x >> 5;
    const int bx = blockIdx.x * 32, by = blockIdx.y * 32;
    #pragma unroll
    for (int j = 0; j < 4; ++j)
        tile[ty + j * 8][tx] = W[(size_t)(by + ty + j * 8) * HID + bx + tx];
    __syncthreads();
    #pragma unroll
    for (int j = 0; j < 4; ++j)
        out[(size_t)(bx + ty + j * 8) * HID + by + tx] = f2bf(tile[tx][ty + j * 8]);
}

// ---------------------------------------------------------------------------
// Kernel 1: fused QKV projection, bf16 MFMA (m97 structure).
// 128x128 tile, BK=32, 4 waves, 4x4 16x16x32 frags/wave, global_load_lds x16.
// xb: [4096][1024] bf16 (row m = s*BATCH+b); wt: 3x[1024][1024] bf16 [n][k].
// z: 0=Q, 1=K (out [bh][s][d]), 2=V (out [bh][d][s]).
// ---------------------------------------------------------------------------
__global__ __launch_bounds__(256) void qkv_mfma(
    const unsigned short* __restrict__ xb,
    const unsigned short* __restrict__ wt,
    const float* __restrict__ bq, const float* __restrict__ bk,
    const float* __restrict__ bv,
    unsigned short* __restrict__ ws_out)
{
    const int bn = blockIdx.x;   // 0..7
    const int bm = blockIdx.y;   // 0..31
    const int z  = blockIdx.z;   // 0..2
    const unsigned short* Bt = wt + (size_t)z * HID * HID;
    const float* bias = (z == 0) ? bq : (z == 1) ? bk : bv;
    unsigned short* out = ws_out + (size_t)z * (size_t)BH * SEQ * HDIM;

    const int t    = threadIdx.x;
    const int wave = t >> 6;
    const int lane = t & 63;
    const int l15  = lane & 15;
    const int quad = lane >> 4;
    const int wm   = (wave >> 1) * 64;
    const int wn   = (wave & 1) * 64;

    // [128 rows][32 bf16] = 64 B/row, unpadded (global_load_lds layout)
    __shared__ __align__(16) unsigned short As[128 * 32];
    __shared__ __align__(16) unsigned short Bs[128 * 32];

    floatx4 acc[4][4];
    #pragma unroll
    for (int i = 0; i < 4; ++i)
        #pragma unroll
        for (int j = 0; j < 4; ++j)
            acc[i][j] = (floatx4){0.f, 0.f, 0.f, 0.f};

    const int lrow = lane >> 2;        // 0..15: row within 16-row issue
    const int lcol = (lane & 3) * 8;   // element col: 0,8,16,24

    for (int kt = 0; kt < HID / 32; ++kt) {
        __syncthreads();               // previous tile fully consumed
        #pragma unroll
        for (int ee = 0; ee < 2; ++ee) {
            const int e = wave * 2 + ee;               // 0..7, wave-uniform
            const unsigned short* ga =
                xb + (size_t)(bm * 128 + e * 16 + lrow) * HID + kt * 32 + lcol;
            const unsigned short* gb =
                Bt + (size_t)(bn * 128 + e * 16 + lrow) * HID + kt * 32 + lcol;
            GLD16(ga, (char*)As + e * 1024);
            GLD16(gb, (char*)Bs + e * 1024);
        }
        __syncthreads();               // staging drained (vmcnt(0) at barrier)

        short8 af[4], bf[4];
        #pragma unroll
        for (int mt = 0; mt < 4; ++mt)
            af[mt] = *(const short8*)&As[(wm + mt * 16 + l15) * 32 + quad * 8];
        #pragma unroll
        for (int nt = 0; nt < 4; ++nt)
            bf[nt] = *(const short8*)&Bs[(wn + nt * 16 + l15) * 32 + quad * 8];
        #pragma unroll
        for (int mt = 0; mt < 4; ++mt)
            #pragma unroll
            for (int nt = 0; nt < 4; ++nt)
                acc[mt][nt] = __builtin_amdgcn_mfma_f32_16x16x32_bf16(
                    af[mt], bf[nt], acc[mt][nt], 0, 0, 0);
    }

    // Epilogue: C[m][n] frag layout: col n = nt*16+l15, rows m = quad*4+r
    #pragma unroll
    for (int nt = 0; nt < 4; ++nt) {
        const int n_g = bn * 128 + wn + nt * 16 + l15;
        const float bsv = bias[n_g];
        const int h = n_g >> 6;
        const int d = n_g & 63;
        #pragma unroll
        for (int mt = 0; mt < 4; ++mt) {
            #pragma unroll
            for (int r = 0; r < 4; ++r) {
                const int m_g = bm * 128 + wm + mt * 16 + quad * 4 + r;
                const int s  = m_g >> 1;      // BATCH == 2
                const int bb = m_g & 1;
                const unsigned short val = f2bf(acc[mt][nt][r] + bsv);
                if (z < 2)
                    out[((size_t)(bb * NHEAD + h) * SEQ + s) * HDIM + d] = val;
                else
                    out[((size_t)(bb * NHEAD + h) * HDIM + d) * SEQ + s] = val;
            }
        }
    }
}

// ---------------------------------------------------------------------------
// Kernel 2: flash attention, bf16 MFMA (16x16x32), fp32 online softmax.
// (unchanged from round 1)
// ---------------------------------------------------------------------------
__global__ __launch_bounds__(256) void attn_mfma(
    const unsigned short* __restrict__ q,
    const unsigned short* __restrict__ k,
    const unsigned short* __restrict__ vt,
    const float* __restrict__ mask,
    float* __restrict__ out)
{
    const int qb   = blockIdx.x;   // 0..31 query tile
    const int n    = blockIdx.y;   // 0..31 flattened head
    const int t    = threadIdx.x;
    const int wave = t >> 6;
    const int lane = t & 63;
    const int l15  = lane & 15;
    const int quad = lane >> 4;
    const int bb   = n >> 4;       // batch
    const int hh   = n & 15;       // head

    __shared__ __align__(16) unsigned short Qs[64][72];
    __shared__ __align__(16) unsigned short Ks[64][72];
    __shared__ __align__(16) unsigned short Vs[64][72];  // [d][key]
    __shared__ __align__(16) unsigned short Ps[64][72];  // [qrow][key]

    const unsigned short* qbase = q + ((size_t)n * SEQ + qb * 64) * HDIM;
    {
        int c = t, r = c >> 3, c8 = (c & 7) * 8;
        *(uint4*)&Qs[r][c8] = *(const uint4*)(qbase + r * HDIM + c8);
        c = t + 256; r = c >> 3; c8 = (c & 7) * 8;
        *(uint4*)&Qs[r][c8] = *(const uint4*)(qbase + r * HDIM + c8);
    }

    floatx4 Of[4];
    #pragma unroll
    for (int nt = 0; nt < 4; ++nt) Of[nt] = (floatx4){0.f, 0.f, 0.f, 0.f};
    float mst = -1e30f, lst = 0.0f;
    const float scale = 0.125f;

    const int qrow_g = qb * 64 + wave * 16 + l15;
    const float* mrow = mask + ((size_t)bb * SEQ + qrow_g) * SEQ;
    const unsigned short* kbase = k + (size_t)n * SEQ * HDIM;
    const unsigned short* vbase = vt + (size_t)n * HDIM * SEQ;

    for (int kt = 0; kt < SEQ / 64; ++kt) {
        __syncthreads();
        {
            const unsigned short* kb = kbase + (size_t)(kt * 64) * HDIM;
            const unsigned short* vb = vbase + kt * 64;
            int c = t, r = c >> 3, c8 = (c & 7) * 8;
            *(uint4*)&Ks[r][c8] = *(const uint4*)(kb + r * HDIM + c8);
            *(uint4*)&Vs[r][c8] = *(const uint4*)(vb + (size_t)r * SEQ + c8);
            c = t + 256; r = c >> 3; c8 = (c & 7) * 8;
            *(uint4*)&Ks[r][c8] = *(const uint4*)(kb + r * HDIM + c8);
            *(uint4*)&Vs[r][c8] = *(const uint4*)(vb + (size_t)r * SEQ + c8);
        }
        __syncthreads();

        floatx4 Sf[4];
        #pragma unroll
        for (int mt = 0; mt < 4; ++mt) {
            floatx4 c = (floatx4){0.f, 0.f, 0.f, 0.f};
            #pragma unroll
            for (int ks = 0; ks < 2; ++ks) {
                short8 a = *(const short8*)&Ks[mt * 16 + l15][ks * 32 + quad * 8];
                short8 b = *(const short8*)&Qs[wave * 16 + l15][ks * 32 + quad * 8];
                c = __builtin_amdgcn_mfma_f32_16x16x32_bf16(a, b, c, 0, 0, 0);
            }
            Sf[mt] = c;
        }

        float sc[4][4];
        float rmax = -1e30f;
        #pragma unroll
        for (int mt = 0; mt < 4; ++mt) {
            const float4 m4 = *(const float4*)(mrow + kt * 64 + mt * 16 + quad * 4);
            const float mv[4] = {m4.x, m4.y, m4.z, m4.w};
            #pragma unroll
            for (int r = 0; r < 4; ++r) {
                sc[mt][r] = Sf[mt][r] * scale + mv[r];
                rmax = fmaxf(rmax, sc[mt][r]);
            }
        }
        rmax = fmaxf(rmax, __shfl_xor(rmax, 16));
        rmax = fmaxf(rmax, __shfl_xor(rmax, 32));

        const float mnew  = fmaxf(mst, rmax);
        const float alpha = __expf(mst - mnew);
        float rsum = 0.0f;
        #pragma unroll
        for (int mt = 0; mt < 4; ++mt)
            #pragma unroll
            for (int r = 0; r < 4; ++r) {
                const float p = __expf(sc[mt][r] - mnew);
                sc[mt][r] = p;
                rsum += p;
            }
        rsum += __shfl_xor(rsum, 16);
        rsum += __shfl_xor(rsum, 32);
        lst = lst * alpha + rsum;
        mst = mnew;

        {
            const float a0 = __shfl(alpha, quad * 4 + 0);
            const float a1 = __shfl(alpha, quad * 4 + 1);
            const float a2 = __shfl(alpha, quad * 4 + 2);
            const float a3 = __shfl(alpha, quad * 4 + 3);
            #pragma unroll
            for (int nt = 0; nt < 4; ++nt) {
                Of[nt][0] *= a0; Of[nt][1] *= a1;
                Of[nt][2] *= a2; Of[nt][3] *= a3;
            }
        }

        #pragma unroll
        for (int mt = 0; mt < 4; ++mt) {
            ushort4 pk;
            pk.x = f2bf(sc[mt][0]);
            pk.y = f2bf(sc[mt][1]);
            pk.z = f2bf(sc[mt][2]);
            pk.w = f2bf(sc[mt][3]);
            *(ushort4*)&Ps[wave * 16 + l15][mt * 16 + quad * 4] = pk;
        }

        #pragma unroll
        for (int ks = 0; ks < 2; ++ks) {
            short8 a = *(const short8*)&Ps[wave * 16 + l15][ks * 32 + quad * 8];
            #pragma unroll
            for (int nt = 0; nt < 4; ++nt) {
                short8 b = *(const short8*)&Vs[nt * 16 + l15][ks * 32 + quad * 8];
                Of[nt] = __builtin_amdgcn_mfma_f32_16x16x32_bf16(a, b, Of[nt], 0, 0, 0);
            }
        }
    }

    #pragma unroll
    for (int r = 0; r < 4; ++r) {
        const float lrow = __shfl(lst, quad * 4 + r);
        const float inv  = 1.0f / lrow;
        const int s = qb * 64 + wave * 16 + quad * 4 + r;
        float* orow = out + ((size_t)s * BATCH + bb) * HID + hh * 64;
        #pragma unroll
        for (int nt = 0; nt < 4; ++nt)
            orow[nt * 16 + l15] = Of[nt][r] * inv;
    }
}

// ---------------------------------------------------------------------------
extern "C" void kernel_launch(void* const* d_in, const int* in_sizes, int n_in,
                              void* d_out, int out_size, void* d_ws, size_t ws_size,
                              hipStream_t stream) {
    const float* x    = (const float*)d_in[0];
    const float* mask = (const float*)d_in[1];
    const float* Wq   = (const float*)d_in[2];
    const float* bq   = (const float*)d_in[3];
    const float* Wk   = (const float*)d_in[4];
    const float* bk   = (const float*)d_in[5];
    const float* Wv   = (const float*)d_in[6];
    const float* bv   = (const float*)d_in[7];
    float* out = (float*)d_out;

    const size_t per = (size_t)BH * SEQ * HDIM;   // 4,194,304 elems = 8 MB bf16
    unsigned short* qw = (unsigned short*)d_ws;   // [0, per)
    unsigned short* kw = qw + per;                // [per, 2per)
    unsigned short* vw = kw + per;                // [2per, 3per)  (V transposed)
    unsigned short* xb = vw + per;                // [3per, 4per)  x bf16
    unsigned short* wt = xb + per;                // 3 x 1M bf16 transposed W

    convert_x<<<dim3(SEQ * BATCH * HID / 4 / 256), dim3(256), 0, stream>>>(x, xb);
    transpose_w<<<dim3(32, 32, 3), dim3(256), 0, stream>>>(Wq, Wk, Wv, wt);

    qkv_mfma<<<dim3(HID / 128, SEQ * BATCH / 128, 3), dim3(256), 0, stream>>>(
        xb, wt, bq, bk, bv, qw);

    attn_mfma<<<dim3(SEQ / 64, BH), dim3(256), 0, stream>>>(qw, kw, vw, mask, out);
}